// Round 4
// baseline (1301.905 us; speedup 1.0000x reference)
//
#include <hip/hip_runtime.h>
#include <hip/hip_bf16.h>

// Decoder: Bahdanau attention + GRU cell + vocab projection
// VOCAB=32000, EMB=512, H=1024, B=64, S=128
// Inputs fp32 (proven: bf16 reads gave NaN, fp32 reads gave finite values;
// reference declares float32). Output fp32 flat: probs(64x32000) |
// state(64x1024) | attn(64x128). dec_input int32.
// Scratch: d_ws when big enough (checked host-side), else inside the probs
// output region (written only before the final kernel).
// Input loads keep a device-side dtype sniff (fp32 vs bf16) as a hedge.

#define B_ 64
#define S_ 128
#define H_ 1024
#define EMB_ 512
#define VOCAB_ 32000

__device__ __forceinline__ float u16f(unsigned short u) {
    return __uint_as_float(((unsigned int)u) << 16);
}
__device__ __forceinline__ float sigmoidf_(float x) { return 1.0f / (1.0f + expf(-x)); }

template <int F32>
__device__ __forceinline__ float gld(const void* p, size_t i) {
    if (F32) return ((const float*)p)[i];
    return u16f(((const unsigned short*)p)[i]);
}

// dtype sniff: bf16 N(0,1) halves have benign exponent fields; fp32 data read
// as 16-bit halves shows ~uniform-random exponents in the mantissa halves.
__global__ void sniff_kernel(const unsigned short* __restrict__ h, int* __restrict__ flag) {
    if (threadIdx.x == 0 && blockIdx.x == 0) {
        int weird = 0;
        for (int i = 0; i < 256; ++i) {
            int e = (h[i] >> 7) & 0xFF;
            if (e != 0 && (e < 0x60 || e > 0x9F)) ++weird;
        }
        *flag = (weird > 8) ? 1 : 0;
    }
}

// C[b,n] = sum_h A[b,h]*W[h,n] + bias[bias_off + n]
template <int AF, int WF>
__device__ void gemm8_body(const void* __restrict__ A, const void* __restrict__ W,
                           const void* __restrict__ bias, int bias_off,
                           float* __restrict__ C, int K, int N) {
    extern __shared__ float a[];
    const int ntiles = N >> 8;
    const int b0 = (blockIdx.x / ntiles) * 8;
    const int n = (blockIdx.x % ntiles) * 256 + threadIdx.x;

    for (int i = threadIdx.x; i < 8 * K; i += 256) {
        int bb = i / K, h = i - bb * K;
        a[i] = gld<AF>(A, (size_t)(b0 + bb) * K + h);
    }
    __syncthreads();

    float bv = gld<WF>(bias, (size_t)bias_off + n);
    float acc[8];
#pragma unroll
    for (int bb = 0; bb < 8; ++bb) acc[bb] = bv;

    for (int h = 0; h < K; ++h) {
        float w = gld<WF>(W, (size_t)h * N + n);
#pragma unroll
        for (int bb = 0; bb < 8; ++bb) acc[bb] += a[bb * K + h] * w;
    }
#pragma unroll
    for (int bb = 0; bb < 8; ++bb) C[(size_t)(b0 + bb) * N + n] = acc[bb];
}

__global__ void gemm8_kernel(const void* A, const void* W, const void* bias, int bias_off,
                             float* C, int K, int N, const int* flag, int a_always_f32) {
    const int wf = *flag;
    if (a_always_f32) {
        if (wf) gemm8_body<1, 1>(A, W, bias, bias_off, C, K, N);
        else    gemm8_body<1, 0>(A, W, bias, bias_off, C, K, N);
    } else {
        if (wf) gemm8_body<1, 1>(A, W, bias, bias_off, C, K, N);
        else    gemm8_body<0, 0>(A, W, bias, bias_off, C, K, N);
    }
}

// score[b,s] = V . tanh(enc[b,s,:] @ W1 + W1_b + hproj[b,:]) + V_b
template <int WF>
__device__ void score_body(const void* __restrict__ enc, const void* __restrict__ W1,
                           const void* __restrict__ W1b, const void* __restrict__ Vk,
                           const void* __restrict__ Vb, const float* __restrict__ hproj,
                           float* __restrict__ score) {
    const int b = blockIdx.x >> 3;
    const int s0 = (blockIdx.x & 7) << 4;
    const int t = threadIdx.x;

    __shared__ float e[16][64];
    __shared__ float red[16][256];

    float acc[16][4];
#pragma unroll
    for (int s = 0; s < 16; ++s)
#pragma unroll
        for (int j = 0; j < 4; ++j) acc[s][j] = 0.0f;

    for (int h0 = 0; h0 < H_; h0 += 64) {
        {
            int s = t >> 4;
            int hh = (t & 15) << 2;
            size_t base = ((size_t)(b * S_ + s0 + s)) * H_ + h0 + hh;
#pragma unroll
            for (int j = 0; j < 4; ++j) e[s][hh + j] = gld<WF>(enc, base + j);
        }
        __syncthreads();
        for (int hh = 0; hh < 64; ++hh) {
            size_t wbase = (size_t)(h0 + hh) * H_ + 4 * t;
            float w0 = gld<WF>(W1, wbase);
            float w1 = gld<WF>(W1, wbase + 1);
            float w2 = gld<WF>(W1, wbase + 2);
            float w3 = gld<WF>(W1, wbase + 3);
#pragma unroll
            for (int s = 0; s < 16; ++s) {
                float ev = e[s][hh];
                acc[s][0] += ev * w0;
                acc[s][1] += ev * w1;
                acc[s][2] += ev * w2;
                acc[s][3] += ev * w3;
            }
        }
        __syncthreads();
    }

    float part[16];
#pragma unroll
    for (int s = 0; s < 16; ++s) part[s] = 0.0f;
#pragma unroll
    for (int j = 0; j < 4; ++j) {
        int k = 4 * t + j;
        float add = gld<WF>(W1b, k) + hproj[(size_t)b * H_ + k];
        float vv = gld<WF>(Vk, k);
#pragma unroll
        for (int s = 0; s < 16; ++s) part[s] += tanhf(acc[s][j] + add) * vv;
    }
#pragma unroll
    for (int s = 0; s < 16; ++s) red[s][t] = part[s];
    __syncthreads();
    for (int str = 128; str > 0; str >>= 1) {
        if (t < str) {
#pragma unroll
            for (int s = 0; s < 16; ++s) red[s][t] += red[s][t + str];
        }
        __syncthreads();
    }
    if (t < 16) score[(size_t)b * S_ + s0 + t] = red[t][0] + gld<WF>(Vb, 0);
}

__global__ void score_kernel(const void* enc, const void* W1, const void* W1b,
                             const void* Vk, const void* Vb, const float* hproj,
                             float* score, const int* flag) {
    if (*flag) score_body<1>(enc, W1, W1b, Vk, Vb, hproj, score);
    else       score_body<0>(enc, W1, W1b, Vk, Vb, hproj, score);
}

// softmax over S per batch -> fp32 attn output region (also the intermediate)
__global__ void softmax_kernel(const float* __restrict__ score,
                               float* __restrict__ attn_out) {
    const int b = blockIdx.x;
    const int s = threadIdx.x;  // 128 threads
    __shared__ float red[128];
    float v = score[b * S_ + s];
    red[s] = v;
    __syncthreads();
    for (int str = 64; str > 0; str >>= 1) {
        if (s < str) red[s] = fmaxf(red[s], red[s + str]);
        __syncthreads();
    }
    float m = red[0];
    __syncthreads();
    float e = expf(v - m);
    red[s] = e;
    __syncthreads();
    for (int str = 64; str > 0; str >>= 1) {
        if (s < str) red[s] += red[s + str];
        __syncthreads();
    }
    attn_out[b * S_ + s] = e / red[0];
}

template <int WF>
__device__ void context_body(const float* __restrict__ attn, const void* __restrict__ enc,
                             float* __restrict__ ctx) {
    const int b = blockIdx.x >> 2;
    const int h = ((blockIdx.x & 3) << 8) + threadIdx.x;
    __shared__ float aw[S_];
    if (threadIdx.x < S_) aw[threadIdx.x] = attn[b * S_ + threadIdx.x];
    __syncthreads();
    float acc = 0.0f;
    for (int s = 0; s < S_; ++s)
        acc += aw[s] * gld<WF>(enc, ((size_t)b * S_ + s) * H_ + h);
    ctx[(size_t)b * H_ + h] = acc;
}

__global__ void context_kernel(const float* attn, const void* enc, float* ctx,
                               const int* flag) {
    if (*flag) context_body<1>(attn, enc, ctx);
    else       context_body<0>(attn, enc, ctx);
}

template <int WF>
__device__ void buildx_body(const float* __restrict__ ctx, const void* __restrict__ emb,
                            const int* __restrict__ dec, float* __restrict__ x) {
    const int b = blockIdx.x;
    const int t = threadIdx.x;
    const int tok = dec[b];
    float* xb = x + (size_t)b * (H_ + EMB_);
    for (int i = t; i < H_; i += 256) xb[i] = ctx[(size_t)b * H_ + i];
    for (int i = t; i < EMB_; i += 256) xb[H_ + i] = gld<WF>(emb, (size_t)tok * EMB_ + i);
}

__global__ void buildx_kernel(const float* ctx, const void* emb, const int* dec, float* x,
                              const int* flag) {
    if (*flag) buildx_body<1>(ctx, emb, dec, x);
    else       buildx_body<0>(ctx, emb, dec, x);
}

// gates: xm and hm both already include their biases (added in gemm8).
// state written fp32 directly to the state output region.
template <int WF>
__device__ void gates_body(const float* __restrict__ xm, const float* __restrict__ hm,
                           const void* __restrict__ hidden, float* __restrict__ state_out) {
    const int idx = blockIdx.x * 256 + threadIdx.x;  // 0..65535
    const int b = idx >> 10, j = idx & (H_ - 1);
    const float* xmb = xm + (size_t)b * 3 * H_;
    const float* hmb = hm + (size_t)b * 3 * H_;
    float z = sigmoidf_(xmb[j] + hmb[j]);
    float r = sigmoidf_(xmb[H_ + j] + hmb[H_ + j]);
    float hc = tanhf(xmb[2 * H_ + j] + r * hmb[2 * H_ + j]);
    float h = gld<WF>(hidden, idx);
    state_out[idx] = z * h + (1.0f - z) * hc;
}

__global__ void gates_kernel(const float* xm, const float* hm, const void* hidden,
                             float* state_out, const int* flag) {
    if (*flag) gates_body<1>(xm, hm, hidden, state_out);
    else       gates_body<0>(xm, hm, hidden, state_out);
}

// probs[b,v] = state[b,:] . out_k[:,v] + out_b[v]; state read fp32 from the
// state output region (disjoint from the probs region being written).
template <int WF>
__device__ void probs_body(const float* __restrict__ state,
                           const void* __restrict__ out_k, const void* __restrict__ out_b,
                           float* __restrict__ probs) {
    const int half = blockIdx.x & 1;
    const int v = (blockIdx.x >> 1) * 256 + threadIdx.x;
    const int b0 = half * 32;
    const int t = threadIdx.x;
    __shared__ float st[32][64];

    float acc[32];
    float bv = gld<WF>(out_b, v);
#pragma unroll
    for (int bb = 0; bb < 32; ++bb) acc[bb] = bv;

    for (int h0 = 0; h0 < H_; h0 += 64) {
        for (int i = t; i < 2048; i += 256) {
            int bb = i >> 6, hh = i & 63;
            st[bb][hh] = state[(size_t)(b0 + bb) * H_ + h0 + hh];
        }
        __syncthreads();
        for (int hh = 0; hh < 64; ++hh) {
            float w = gld<WF>(out_k, (size_t)(h0 + hh) * VOCAB_ + v);
#pragma unroll
            for (int bb = 0; bb < 32; ++bb) acc[bb] += st[bb][hh] * w;
        }
        __syncthreads();
    }
#pragma unroll
    for (int bb = 0; bb < 32; ++bb)
        probs[(size_t)(b0 + bb) * VOCAB_ + v] = acc[bb];
}

__global__ void probs_kernel(const float* state, const void* out_k, const void* out_b,
                             float* probs, const int* flag) {
    if (*flag) probs_body<1>(state, out_k, out_b, probs);
    else       probs_body<0>(state, out_k, out_b, probs);
}

// ---------------------------------------------------------------------------
extern "C" void kernel_launch(void* const* d_in, const int* in_sizes, int n_in,
                              void* d_out, int out_size, void* d_ws, size_t ws_size,
                              hipStream_t stream) {
    const int* dec_input = (const int*)d_in[0];
    const void* hidden = d_in[1];
    const void* enc = d_in[2];
    const void* emb = d_in[3];
    const void* W1_k = d_in[4];
    const void* W1_b = d_in[5];
    const void* W2_k = d_in[6];
    const void* W2_b = d_in[7];
    const void* V_k = d_in[8];
    const void* V_b = d_in[9];
    const void* gru_k = d_in[10];
    const void* gru_rk = d_in[11];
    const void* gru_b = d_in[12];
    const void* out_k = d_in[13];
    const void* out_b = d_in[14];

    float* out = (float*)d_out;
    float* probs_out = out;                              // 64*32000 fp32
    float* state_out = out + (size_t)B_ * VOCAB_;        // 64*1024  fp32
    float* attn_out = state_out + (size_t)B_ * H_;       // 64*128   fp32

    // scratch layout (floats): hproj 65536 | hm 196608 | score 8192 |
    // ctx 65536 | xvec 98304 | xm 196608 | flag 1  -> 630,913 floats
    const size_t NEED_F = 630913;
    float* scratch = (ws_size >= NEED_F * sizeof(float)) ? (float*)d_ws
                                                         : probs_out;  // fallback
    float* hproj = scratch;
    float* hm = hproj + B_ * H_;
    float* score = hm + B_ * 3 * H_;
    float* ctx = score + B_ * S_;
    float* xvec = ctx + B_ * H_;
    float* xm = xvec + B_ * (H_ + EMB_);
    int* flag = (int*)(xm + B_ * 3 * H_);

    // 0. dtype sniff (hedge; expected fp32 -> flag=1)
    sniff_kernel<<<1, 64, 0, stream>>>((const unsigned short*)hidden, flag);
    // 1. hproj = hidden @ W2_k + W2_b
    gemm8_kernel<<<(B_ / 8) * (H_ / 256), 256, 8 * H_ * 4, stream>>>(
        hidden, W2_k, W2_b, 0, hproj, H_, H_, flag, 0);
    // 2. hm = hidden @ gru_rk + gru_b[1]  (bias row 1 = element offset 3H)
    gemm8_kernel<<<(B_ / 8) * (3 * H_ / 256), 256, 8 * H_ * 4, stream>>>(
        hidden, gru_rk, gru_b, 3 * H_, hm, H_, 3 * H_, flag, 0);
    // 3. score
    score_kernel<<<B_ * (S_ / 16), 256, 0, stream>>>(enc, W1_k, W1_b, V_k, V_b, hproj,
                                                     score, flag);
    // 4. softmax -> attn output region (fp32)
    softmax_kernel<<<B_, S_, 0, stream>>>(score, attn_out);
    // 5. context (reads attn output region)
    context_kernel<<<B_ * (H_ / 256), 256, 0, stream>>>(attn_out, enc, ctx, flag);
    // 6. x = concat(context, emb[dec])
    buildx_kernel<<<B_, 256, 0, stream>>>(ctx, emb, dec_input, xvec, flag);
    // 7. xm = x @ gru_k + gru_b[0]
    gemm8_kernel<<<(B_ / 8) * (3 * H_ / 256), 256, 8 * (H_ + EMB_) * 4, stream>>>(
        xvec, gru_k, gru_b, 0, xm, H_ + EMB_, 3 * H_, flag, 1);
    // 8. gates -> state output region (fp32)
    gates_kernel<<<(B_ * H_) / 256, 256, 0, stream>>>(xm, hm, hidden, state_out, flag);
    // 9. probs -> probs output region (overwrites fallback scratch if used)
    probs_kernel<<<(VOCAB_ / 256) * 2, 256, 0, stream>>>(state_out, out_k, out_b,
                                                         probs_out, flag);
}

// Round 5
// 614.308 us; speedup vs baseline: 2.1193x; 2.1193x over previous
//
#include <hip/hip_runtime.h>

// Decoder: Bahdanau attention + GRU cell + vocab projection
// VOCAB=32000, EMB=512, H=1024, B=64, S=128
// Inputs fp32, dec_input int32. Output fp32 flat:
//   probs(64x32000) | state(64x1024) | attn(64x128)
// GEMMs via bf16 MFMA (v_mfma_f32_16x16x32_bf16), fp32 accumulate.
// Verified fragment layouts (learn_hip m89/m91/m120):
//   A: lane holds A[m=lane&15][k=(lane>>4)*8 + j], j=0..7 (8 bf16, b128)
//   B: lane holds B[k=(lane>>4)*8 + j][n=lane&15]
//   C/D: row=(lane>>4)*4+reg, col=lane&15

#define B_ 64
#define S_ 128
#define H_ 1024
#define EMB_ 512
#define VOCAB_ 32000

typedef __attribute__((ext_vector_type(8))) short short8;
typedef __attribute__((ext_vector_type(4))) short short4v;
typedef __attribute__((ext_vector_type(4))) float f32x4;

__device__ __forceinline__ unsigned short f2bf_bits(float f) {
    unsigned int u = __float_as_uint(f);
    u += 0x7FFF + ((u >> 16) & 1);  // round-to-nearest-even
    return (unsigned short)(u >> 16);
}
__device__ __forceinline__ float sigmoidf_(float x) { return 1.0f / (1.0f + expf(-x)); }

// ---------------------------------------------------------------------------
// Tile GEMM core: C_tile(64 x 64*NF) += A(64xK slice) * W(K x N) over k0..k1.
// A fp32 row-major (lda), W fp32 row-major (ldw). bf16 conversion on the fly.
// Block = 256 threads = 4 waves; wave w covers cols [w*16*NF, w*16*NF+16*NF).
// LDS: A_lds[row][k] rowstride 40 shorts; B_lds[n][k] rowstride 40 (transposed
// staging so B-frag reads are contiguous ds_read_b128).
// ---------------------------------------------------------------------------
template <int NF>
__device__ void mfma_gemm_tile(const float* __restrict__ A, int lda,
                               const float* __restrict__ W, int ldw,
                               int m_base, int n_base, int k0, int k1,
                               f32x4 (&acc)[4][NF]) {
    __shared__ unsigned short A_lds[64 * 40];
    __shared__ unsigned short B_lds[64 * NF * 40];
    const int tid = threadIdx.x;
    const int w = tid >> 6, lane = tid & 63, quad = lane >> 4, l15 = lane & 15;

    const f32x4 z = {0.0f, 0.0f, 0.0f, 0.0f};
#pragma unroll
    for (int mi = 0; mi < 4; ++mi)
#pragma unroll
        for (int ni = 0; ni < NF; ++ni) acc[mi][ni] = z;

    for (int k = k0; k < k1; k += 32) {
        // stage A: 64 rows x 32 k (fp32 -> bf16), [row][k]
#pragma unroll
        for (int it = 0; it < 2; ++it) {
            int idx = tid + 256 * it;        // 0..511
            int r = idx >> 3, c = idx & 7;   // float4 group c
            float4 v = *(const float4*)(A + (size_t)(m_base + r) * lda + k + 4 * c);
            short4v s;
            s.x = (short)f2bf_bits(v.x);
            s.y = (short)f2bf_bits(v.y);
            s.z = (short)f2bf_bits(v.z);
            s.w = (short)f2bf_bits(v.w);
            *(short4v*)&A_lds[r * 40 + 4 * c] = s;
        }
        // stage B transposed: 32 k-rows x 64*NF cols -> B_lds[n][k]
        constexpr int CG = 16 * NF;  // float4 groups per k-row
#pragma unroll
        for (int it = 0; it < 2 * NF; ++it) {
            int idx = tid + 256 * it;        // 0 .. 32*CG-1
            int kr = idx / CG, c = idx % CG;
            float4 v = *(const float4*)(W + (size_t)(k + kr) * ldw + n_base + 4 * c);
            int n = 4 * c;
            B_lds[(n + 0) * 40 + kr] = f2bf_bits(v.x);
            B_lds[(n + 1) * 40 + kr] = f2bf_bits(v.y);
            B_lds[(n + 2) * 40 + kr] = f2bf_bits(v.z);
            B_lds[(n + 3) * 40 + kr] = f2bf_bits(v.w);
        }
        __syncthreads();

        short8 bfrag[NF];
#pragma unroll
        for (int ni = 0; ni < NF; ++ni) {
            int n = w * 16 * NF + 16 * ni + l15;
            bfrag[ni] = *(const short8*)&B_lds[n * 40 + quad * 8];
        }
#pragma unroll
        for (int mi = 0; mi < 4; ++mi) {
            short8 afrag = *(const short8*)&A_lds[(16 * mi + l15) * 40 + quad * 8];
#pragma unroll
            for (int ni = 0; ni < NF; ++ni)
                acc[mi][ni] = __builtin_amdgcn_mfma_f32_16x16x32_bf16(
                    afrag, bfrag[ni], acc[mi][ni], 0, 0, 0);
        }
        __syncthreads();
    }
}

// ---------------------------------------------------------------------------
// C[i] = bias[bias_off + i % N]  (pre-init for atomic-accumulate GEMMs)
// ---------------------------------------------------------------------------
__global__ void init_bias_kernel(float* __restrict__ C, const float* __restrict__ bias,
                                 int bias_off, int N, int total) {
    int i = blockIdx.x * 256 + threadIdx.x;
    if (i < total) C[i] = bias[bias_off + (i % N)];
}

// ---------------------------------------------------------------------------
// Skinny GEMM (M=64), K-split across blockIdx.y, atomicAdd into pre-inited C.
// ---------------------------------------------------------------------------
template <int NF>
__global__ __launch_bounds__(256) void gemm_mfma_atomic_kernel(
    const float* __restrict__ A, int lda, const float* __restrict__ W, int ldw,
    float* __restrict__ C, int kslice) {
    f32x4 acc[4][NF];
    const int n_base = blockIdx.x * 64 * NF;
    const int k0 = blockIdx.y * kslice;
    mfma_gemm_tile<NF>(A, lda, W, ldw, 0, n_base, k0, k0 + kslice, acc);
    const int tid = threadIdx.x, w = tid >> 6, lane = tid & 63;
    const int quad = lane >> 4, l15 = lane & 15;
#pragma unroll
    for (int mi = 0; mi < 4; ++mi)
#pragma unroll
        for (int ni = 0; ni < NF; ++ni) {
            int col = n_base + w * 16 * NF + 16 * ni + l15;
#pragma unroll
            for (int r = 0; r < 4; ++r) {
                int row = 16 * mi + quad * 4 + r;
                atomicAdd(&C[(size_t)row * ldw + col], acc[mi][ni][r]);
            }
        }
}

// ---------------------------------------------------------------------------
// score: feat = enc @ W1 (this block: 64 (b,s)-rows x 256 feat-cols), then
// partial score = sum_k tanh(feat + W1b[k] + hproj[b][k]) * Vk[k], reduced
// across the 16 lanes sharing a quad, atomicAdd into V_b-pre-inited score.
// ---------------------------------------------------------------------------
__global__ __launch_bounds__(256) void score_mfma_kernel(
    const float* __restrict__ enc, const float* __restrict__ W1,
    const float* __restrict__ W1b, const float* __restrict__ Vk,
    const float* __restrict__ hproj, float* __restrict__ score) {
    f32x4 acc[4][4];
    const int n_base = blockIdx.x * 256;
    const int m_base = blockIdx.y * 64;
    const int b = m_base >> 7, s_base = m_base & 127;
    mfma_gemm_tile<4>(enc, H_, W1, H_, m_base, n_base, 0, H_, acc);

    const int tid = threadIdx.x, w = tid >> 6, lane = tid & 63;
    const int quad = lane >> 4, l15 = lane & 15;

    float rowpart[4][4];
#pragma unroll
    for (int mi = 0; mi < 4; ++mi)
#pragma unroll
        for (int r = 0; r < 4; ++r) rowpart[mi][r] = 0.0f;

#pragma unroll
    for (int ni = 0; ni < 4; ++ni) {
        int kcol = n_base + w * 64 + 16 * ni + l15;
        float add = W1b[kcol] + hproj[(size_t)b * H_ + kcol];
        float vv = Vk[kcol];
#pragma unroll
        for (int mi = 0; mi < 4; ++mi)
#pragma unroll
            for (int r = 0; r < 4; ++r)
                rowpart[mi][r] += tanhf(acc[mi][ni][r] + add) * vv;
    }
    // reduce across the 16 lanes with the same quad (xor over bits 0..3)
#pragma unroll
    for (int m = 1; m <= 8; m <<= 1)
#pragma unroll
        for (int mi = 0; mi < 4; ++mi)
#pragma unroll
            for (int r = 0; r < 4; ++r)
                rowpart[mi][r] += __shfl_xor(rowpart[mi][r], m, 64);
    if (l15 == 0) {
#pragma unroll
        for (int mi = 0; mi < 4; ++mi)
#pragma unroll
            for (int r = 0; r < 4; ++r)
                atomicAdd(&score[b * S_ + s_base + 16 * mi + quad * 4 + r],
                          rowpart[mi][r]);
    }
}

// ---------------------------------------------------------------------------
// probs = state @ out_k + out_b (M=64, N=32000, K=1024), direct store.
// ---------------------------------------------------------------------------
__global__ __launch_bounds__(256) void probs_mfma_kernel(
    const float* __restrict__ state, const float* __restrict__ out_k,
    const float* __restrict__ out_b, float* __restrict__ probs) {
    f32x4 acc[4][2];
    const int n_base = blockIdx.x * 128;
    mfma_gemm_tile<2>(state, H_, out_k, VOCAB_, 0, n_base, 0, H_, acc);
    const int tid = threadIdx.x, w = tid >> 6, lane = tid & 63;
    const int quad = lane >> 4, l15 = lane & 15;
#pragma unroll
    for (int mi = 0; mi < 4; ++mi)
#pragma unroll
        for (int ni = 0; ni < 2; ++ni) {
            int col = n_base + w * 32 + 16 * ni + l15;
            float bv = out_b[col];
#pragma unroll
            for (int r = 0; r < 4; ++r) {
                int row = 16 * mi + quad * 4 + r;
                probs[(size_t)row * VOCAB_ + col] = acc[mi][ni][r] + bv;
            }
        }
}

// ---------------------------------------------------------------------------
// softmax over S per batch -> fp32 attn output region
// ---------------------------------------------------------------------------
__global__ void softmax_kernel(const float* __restrict__ score,
                               float* __restrict__ attn_out) {
    const int b = blockIdx.x;
    const int s = threadIdx.x;  // 128 threads
    __shared__ float red[128];
    float v = score[b * S_ + s];
    red[s] = v;
    __syncthreads();
    for (int str = 64; str > 0; str >>= 1) {
        if (s < str) red[s] = fmaxf(red[s], red[s + str]);
        __syncthreads();
    }
    float m = red[0];
    __syncthreads();
    float e = expf(v - m);
    red[s] = e;
    __syncthreads();
    for (int str = 64; str > 0; str >>= 1) {
        if (s < str) red[s] += red[s + str];
        __syncthreads();
    }
    attn_out[b * S_ + s] = e / red[0];
}

// ---------------------------------------------------------------------------
// context[b,h] = sum_s attn[b,s] * enc[b,s,h]
// ---------------------------------------------------------------------------
__global__ void context_kernel(const float* __restrict__ attn,
                               const float* __restrict__ enc,
                               float* __restrict__ ctx) {
    const int b = blockIdx.x >> 2;
    const int h = ((blockIdx.x & 3) << 8) + threadIdx.x;
    __shared__ float aw[S_];
    if (threadIdx.x < S_) aw[threadIdx.x] = attn[b * S_ + threadIdx.x];
    __syncthreads();
    float acc = 0.0f;
    for (int s = 0; s < S_; ++s)
        acc += aw[s] * enc[((size_t)b * S_ + s) * H_ + h];
    ctx[(size_t)b * H_ + h] = acc;
}

// ---------------------------------------------------------------------------
// x[b,:] = concat(context[b,:], emb[dec[b],:])
// ---------------------------------------------------------------------------
__global__ void buildx_kernel(const float* __restrict__ ctx, const float* __restrict__ emb,
                              const int* __restrict__ dec, float* __restrict__ x) {
    const int b = blockIdx.x;
    const int t = threadIdx.x;
    const int tok = dec[b];
    float* xb = x + (size_t)b * (H_ + EMB_);
    for (int i = t; i < H_; i += 256) xb[i] = ctx[(size_t)b * H_ + i];
    for (int i = t; i < EMB_; i += 256) xb[H_ + i] = emb[(size_t)tok * EMB_ + i];
}

// ---------------------------------------------------------------------------
// GRU gates (xm/hm already include their biases): state -> fp32 output region
// ---------------------------------------------------------------------------
__global__ void gates_kernel(const float* __restrict__ xm, const float* __restrict__ hm,
                             const float* __restrict__ hidden,
                             float* __restrict__ state_out) {
    const int idx = blockIdx.x * 256 + threadIdx.x;  // 0..65535
    const int b = idx >> 10, j = idx & (H_ - 1);
    const float* xmb = xm + (size_t)b * 3 * H_;
    const float* hmb = hm + (size_t)b * 3 * H_;
    float z = sigmoidf_(xmb[j] + hmb[j]);
    float r = sigmoidf_(xmb[H_ + j] + hmb[H_ + j]);
    float hc = tanhf(xmb[2 * H_ + j] + r * hmb[2 * H_ + j]);
    state_out[idx] = z * hidden[idx] + (1.0f - z) * hc;
}

// ---------------------------------------------------------------------------
extern "C" void kernel_launch(void* const* d_in, const int* in_sizes, int n_in,
                              void* d_out, int out_size, void* d_ws, size_t ws_size,
                              hipStream_t stream) {
    const int* dec_input = (const int*)d_in[0];
    const float* hidden = (const float*)d_in[1];
    const float* enc = (const float*)d_in[2];
    const float* emb = (const float*)d_in[3];
    const float* W1_k = (const float*)d_in[4];
    const float* W1_b = (const float*)d_in[5];
    const float* W2_k = (const float*)d_in[6];
    const float* W2_b = (const float*)d_in[7];
    const float* V_k = (const float*)d_in[8];
    const float* V_b = (const float*)d_in[9];
    const float* gru_k = (const float*)d_in[10];
    const float* gru_rk = (const float*)d_in[11];
    const float* gru_b = (const float*)d_in[12];
    const float* out_k = (const float*)d_in[13];
    const float* out_b = (const float*)d_in[14];

    float* out = (float*)d_out;
    float* probs_out = out;                              // 64*32000
    float* state_out = out + (size_t)B_ * VOCAB_;        // 64*1024
    float* attn_out = state_out + (size_t)B_ * H_;       // 64*128

    // scratch (floats): hproj 65536 | hm 196608 | score 8192 | ctx 65536 |
    // xvec 98304 | xm 196608  -> 630,784 floats (2.52 MB)
    const size_t NEED_F = 630784;
    float* scratch = (ws_size >= NEED_F * sizeof(float)) ? (float*)d_ws
                                                         : probs_out;  // fallback
    float* hproj = scratch;
    float* hm = hproj + B_ * H_;
    float* score = hm + B_ * 3 * H_;
    float* ctx = score + B_ * S_;
    float* xvec = ctx + B_ * H_;
    float* xm = xvec + B_ * (H_ + EMB_);

    // --- pre-init accumulators with biases ---
    init_bias_kernel<<<(B_ * H_ + 255) / 256, 256, 0, stream>>>(hproj, W2_b, 0, H_, B_ * H_);
    init_bias_kernel<<<(B_ * 3 * H_ + 255) / 256, 256, 0, stream>>>(hm, gru_b, 3 * H_,
                                                                    3 * H_, B_ * 3 * H_);
    init_bias_kernel<<<(B_ * S_ + 255) / 256, 256, 0, stream>>>(score, V_b, 0, 1, B_ * S_);
    init_bias_kernel<<<(B_ * 3 * H_ + 255) / 256, 256, 0, stream>>>(xm, gru_b, 0, 3 * H_,
                                                                    B_ * 3 * H_);

    // 1. hproj += hidden @ W2_k   (N=1024: 16 n-tiles x KS=4 -> 64 blocks)
    gemm_mfma_atomic_kernel<1><<<dim3(16, 4), 256, 0, stream>>>(hidden, H_, W2_k, H_,
                                                                hproj, H_ / 4);
    // 2. hm += hidden @ gru_rk    (N=3072: 48 x KS=2 -> 96 blocks)
    gemm_mfma_atomic_kernel<1><<<dim3(48, 2), 256, 0, stream>>>(hidden, H_, gru_rk,
                                                                3 * H_, hm, H_ / 2);
    // 3. score += fused tanh/V epilogue of enc @ W1  (4 k-tiles x 128 m-tiles)
    score_mfma_kernel<<<dim3(4, 128), 256, 0, stream>>>(enc, W1_k, W1_b, V_k, hproj,
                                                        score);
    // 4. softmax -> attn output region
    softmax_kernel<<<B_, S_, 0, stream>>>(score, attn_out);
    // 5. context
    context_kernel<<<B_ * (H_ / 256), 256, 0, stream>>>(attn_out, enc, ctx);
    // 6. x = concat(context, emb[dec])
    buildx_kernel<<<B_, 256, 0, stream>>>(ctx, emb, dec_input, xvec);
    // 7. xm += x @ gru_k          (K=1536: 48 x KS=2 -> 96 blocks)
    gemm_mfma_atomic_kernel<1><<<dim3(48, 2), 256, 0, stream>>>(xvec, H_ + EMB_, gru_k,
                                                                3 * H_, xm, (H_ + EMB_) / 2);
    // 8. gates -> state output region
    gates_kernel<<<(B_ * H_) / 256, 256, 0, stream>>>(xm, hm, hidden, state_out);
    // 9. probs = state @ out_k + out_b  (250 blocks, direct store)
    probs_mfma_kernel<<<dim3(VOCAB_ / 128), 256, 0, stream>>>(state_out, out_k, out_b,
                                                              probs_out);
}